// Round 1
// baseline (164.255 us; speedup 1.0000x reference)
//
#include <hip/hip_runtime.h>

#define NUM_ROI 148
#define NQ 5
#define NN 131072
#define ROI_SPLIT 4
#define ROI_PER (NUM_ROI / ROI_SPLIT)  // 37

// Each thread: 4 consecutive n. Grid y splits the 148 ROIs into 4 groups of 37
// so grid = 128x4 = 512 blocks (2 blocks/CU, 8 waves/CU).
// Weights packed [wr0..4, br, wfx, wf0..4, bf, pad x3] = 16 floats/roi in LDS,
// read back as 3 x ds_read_b128 + 1 b32 (wave-uniform addr -> broadcast).
__global__ __launch_bounds__(256) void coconet_kernel(
    const float* __restrict__ X, const float* __restrict__ Z,
    const float* __restrict__ Wr, const float* __restrict__ br,
    const float* __restrict__ Wf, const float* __restrict__ bf,
    float* __restrict__ out)
{
    __shared__ float w[ROI_PER][16];
    const int tid = threadIdx.x;
    const int roiBase = blockIdx.y * ROI_PER;

    if (tid < ROI_PER) {
        const int r = roiBase + tid;
        #pragma unroll
        for (int q = 0; q < NQ; ++q) w[tid][q] = Wr[r * NQ + q];
        w[tid][5] = br[r];
        #pragma unroll
        for (int d = 0; d < 6; ++d) w[tid][6 + d] = Wf[r * 6 + d];
        w[tid][12] = bf[r];
    }
    __syncthreads();

    const int n0 = (blockIdx.x * 256 + tid) * 4;

    // X[n0..n0+3]
    const float4 x4 = *reinterpret_cast<const float4*>(X + n0);
    const float x[4] = {x4.x, x4.y, x4.z, x4.w};

    // Z rows n0..n0+3: 20 contiguous floats starting at n0*5 (16B-aligned since n0%4==0)
    float z[4][NQ];
    {
        const float4* zp = reinterpret_cast<const float4*>(Z + (size_t)n0 * NQ);
        const float4 a = zp[0], b = zp[1], c = zp[2], d = zp[3], e = zp[4];
        const float tmp[20] = {a.x, a.y, a.z, a.w, b.x, b.y, b.z, b.w,
                               c.x, c.y, c.z, c.w, d.x, d.y, d.z, d.w,
                               e.x, e.y, e.z, e.w};
        #pragma unroll
        for (int j = 0; j < 4; ++j)
            #pragma unroll
            for (int q = 0; q < NQ; ++q) z[j][q] = tmp[j * NQ + q];
    }

    float* outR = out + (size_t)roiBase * NN + n0;
    float* outF = out + (size_t)(NUM_ROI + roiBase) * NN + n0;

    for (int i = 0; i < ROI_PER; ++i) {
        const float4 w0 = *reinterpret_cast<const float4*>(&w[i][0]);  // wr0..wr3
        const float4 w1 = *reinterpret_cast<const float4*>(&w[i][4]);  // wr4, br, wfx, wf0
        const float4 w2 = *reinterpret_cast<const float4*>(&w[i][8]);  // wf1..wf4
        const float bfv = w[i][12];
        const float wr[NQ] = {w0.x, w0.y, w0.z, w0.w, w1.x};
        const float brv = w1.y, wfx = w1.z;
        const float wf[NQ] = {w1.w, w2.x, w2.y, w2.z, w2.w};

        float rr[4], ff[4];
        #pragma unroll
        for (int j = 0; j < 4; ++j) {
            float r_ = brv;
            float f_ = fmaf(x[j], wfx, bfv);
            #pragma unroll
            for (int q = 0; q < NQ; ++q) {
                r_ = fmaf(z[j][q], wr[q], r_);
                f_ = fmaf(z[j][q], wf[q], f_);
            }
            rr[j] = r_;
            ff[j] = f_;
        }
        *reinterpret_cast<float4*>(outR) = make_float4(rr[0], rr[1], rr[2], rr[3]);
        *reinterpret_cast<float4*>(outF) = make_float4(ff[0], ff[1], ff[2], ff[3]);
        outR += NN;
        outF += NN;
    }
}

extern "C" void kernel_launch(void* const* d_in, const int* in_sizes, int n_in,
                              void* d_out, int out_size, void* d_ws, size_t ws_size,
                              hipStream_t stream) {
    const float* X  = (const float*)d_in[0];
    const float* Z  = (const float*)d_in[1];
    const float* Wr = (const float*)d_in[2];
    const float* br = (const float*)d_in[3];
    const float* Wf = (const float*)d_in[4];
    const float* bf = (const float*)d_in[5];
    float* out = (float*)d_out;

    dim3 grid(NN / (256 * 4), ROI_SPLIT);  // 128 x 4 = 512 blocks
    coconet_kernel<<<grid, 256, 0, stream>>>(X, Z, Wr, br, Wf, bf, out);
}